// Round 1
// baseline (80.641 us; speedup 1.0000x reference)
//
#include <hip/hip_runtime.h>
#include <math.h>

// Problem constants (fixed by setup_inputs in the reference)
#define HH   512
#define NST  32
#define MM   2
#define LL   2048
#define NS   (MM * NST)   // 64 fractional states per h
#define TL   8            // l-elements per thread; 256 threads * 8 = 2048 = L

// K[h,l] = 2 * Re( sum_s C_disc[h,s] * exp(dtA[h,s] * l) )
// Strategy: per-block (one h) state table in LDS; per thread, for each state,
// start z = exp(dtA*l0) directly (exp+sincos), then geometric recurrence
// z *= w over 8 consecutive l. Two states interleaved for ILP.
__global__ __launch_bounds__(256) void loong_kernel(
    const float* __restrict__ C_real,      // [1, H, NST, 2]
    const float* __restrict__ log_dt,      // [H]
    const float* __restrict__ log_A_real,  // [H, NST]
    const float* __restrict__ A_imag,      // [H, NST]
    const float* __restrict__ omega_logit, // [M]
    const float* __restrict__ eta_logit,   // [M]
    float* __restrict__ out)               // [1, H, L]
{
    __shared__ float sCdr[NS], sCdi[NS], swr[NS], swi[NS], sar[NS], sai[NS];
    const int h = blockIdx.x;
    const int t = threadIdx.x;

    // ---- Preamble: 64 threads compute the per-state discretized params ----
    if (t < NS) {
        const int m = t >> 5;   // 0..1
        const int n = t & 31;   // 0..31
        const float dt  = __expf(log_dt[h]);
        const float Are = -__expf(log_A_real[h * NST + n]);
        const float Aim = A_imag[h * NST + n];
        const float om = 1e-6f + (100.0f - 1e-6f) * (1.0f / (1.0f + __expf(-omega_logit[m])));
        const float et = 1e-6f + (10.0f  - 1e-6f) * (1.0f / (1.0f + __expf(-eta_logit[m])));
        const float Afr = fmaf(et, Are, -om);       // -omega + eta*Re(A)
        const float Afi = et * Aim;                 //          eta*Im(A)
        const float Cfr = et * C_real[(h * NST + n) * 2 + 0];
        const float Cfi = et * C_real[(h * NST + n) * 2 + 1];
        const float ar = dt * Afr, ai = dt * Afi;   // dtA
        const float e  = __expf(ar);
        float sn, cs;
        __sincosf(ai, &sn, &cs);
        const float Er = e * cs, Ei = e * sn;       // exp(dtA)
        // C_disc = C_frac * (exp(dtA)-1) / (A_frac + 1e-8)
        const float dr = Afr + 1e-8f, di = Afi;
        const float inv = 1.0f / fmaf(dr, dr, di * di);
        const float numr = Er - 1.0f, numi = Ei;
        const float qr = fmaf(numr, dr,  numi * di) * inv;
        const float qi = fmaf(numi, dr, -numr * di) * inv;
        float Cdr = fmaf(Cfr, qr, -(Cfi * qi));
        float Cdi = fmaf(Cfr, qi,  (Cfi * qr));
        if (sqrtf(fmaf(Afr, Afr, Afi * Afi)) < 1e-6f) {   // |A_frac| small branch
            Cdr = Cfr * dt;
            Cdi = Cfi * dt;
        }
        sCdr[t] = 2.0f * Cdr;   // fold the final 2.0 * Re(...) factor in
        sCdi[t] = 2.0f * Cdi;
        swr[t] = Er;  swi[t] = Ei;    // recurrence multiplier w = exp(dtA)
        sar[t] = ar;  sai[t] = ai;    // for direct z0 = exp(dtA * l0)
    }
    __syncthreads();

    float acc[TL];
#pragma unroll
    for (int j = 0; j < TL; ++j) acc[j] = 0.0f;

    const float l0 = (float)(t * TL);

    for (int s = 0; s < NS; s += 2) {
        // chunk-start values z0 = exp(dtA * l0), computed directly (bounds drift)
        const float ar0 = sar[s],     ai0 = sai[s];
        const float ar1 = sar[s + 1], ai1 = sai[s + 1];
        const float e0 = __expf(ar0 * l0);
        const float e1 = __expf(ar1 * l0);
        float s0, c0, s1, c1;
        __sincosf(ai0 * l0, &s0, &c0);
        __sincosf(ai1 * l0, &s1, &c1);
        float zr0 = e0 * c0, zi0 = e0 * s0;
        float zr1 = e1 * c1, zi1 = e1 * s1;
        const float wr0 = swr[s],     wi0 = swi[s];
        const float wr1 = swr[s + 1], wi1 = swi[s + 1];
        const float Cr0 = sCdr[s],     Ci0 = sCdi[s];
        const float Cr1 = sCdr[s + 1], Ci1 = sCdi[s + 1];
#pragma unroll
        for (int j = 0; j < TL; ++j) {
            acc[j] = fmaf(Cr0, zr0, acc[j]);
            acc[j] = fmaf(-Ci0, zi0, acc[j]);
            acc[j] = fmaf(Cr1, zr1, acc[j]);
            acc[j] = fmaf(-Ci1, zi1, acc[j]);
            const float nzr0 = fmaf(zr0, wr0, -(zi0 * wi0));
            const float nzi0 = fmaf(zr0, wi0,  (zi0 * wr0));
            const float nzr1 = fmaf(zr1, wr1, -(zi1 * wi1));
            const float nzi1 = fmaf(zr1, wi1,  (zi1 * wr1));
            zr0 = nzr0; zi0 = nzi0;
            zr1 = nzr1; zi1 = nzi1;
        }
    }

    float4* o = reinterpret_cast<float4*>(out + (size_t)h * LL + (size_t)t * TL);
    o[0] = make_float4(acc[0], acc[1], acc[2], acc[3]);
    o[1] = make_float4(acc[4], acc[5], acc[6], acc[7]);
}

extern "C" void kernel_launch(void* const* d_in, const int* in_sizes, int n_in,
                              void* d_out, int out_size, void* d_ws, size_t ws_size,
                              hipStream_t stream) {
    const float* C_real      = (const float*)d_in[0];
    const float* log_dt      = (const float*)d_in[1];
    const float* log_A_real  = (const float*)d_in[2];
    const float* A_imag      = (const float*)d_in[3];
    const float* omega_logit = (const float*)d_in[4];
    const float* eta_logit   = (const float*)d_in[5];
    float* out = (float*)d_out;

    loong_kernel<<<dim3(HH), dim3(256), 0, stream>>>(
        C_real, log_dt, log_A_real, A_imag, omega_logit, eta_logit, out);
}

// Round 2
// 78.929 us; speedup vs baseline: 1.0217x; 1.0217x over previous
//
#include <hip/hip_runtime.h>
#include <math.h>

// Problem constants (fixed by setup_inputs in the reference)
#define HH      512
#define NST     32
#define MM      2
#define LL      2048
#define NS      (MM * NST)   // 64 fractional states per h
#define TL      4            // l-elements per thread
#define NCHUNK  2            // L-chunks per h -> 1024 blocks -> 4 waves/SIMD
#define CHUNK_L (256 * TL)   // 1024

#define TWO_PI     6.2831853071795864f
#define INV_TWO_PI 0.15915494309189535f

// K[h,l] = 2 * Re( sum_s C_disc[h,s] * exp(dtA[h,s] * l) )
// y-trick: y = C_disc * z, y <- y*w, acc += Re(y).  Chunk-start init uses
// revolutions-based range reduction so sincos args are always < 2*pi
// (no accurate/Payne-Hanek path with huge radian arguments).
__global__ __launch_bounds__(256) void loong_kernel(
    const float* __restrict__ C_real,      // [1, H, NST, 2]
    const float* __restrict__ log_dt,      // [H]
    const float* __restrict__ log_A_real,  // [H, NST]
    const float* __restrict__ A_imag,      // [H, NST]
    const float* __restrict__ omega_logit, // [M]
    const float* __restrict__ eta_logit,   // [M]
    float* __restrict__ out)               // [1, H, L]
{
    __shared__ float4 sP[NS];  // {2*Cdr, 2*Cdi, wr, wi}   w = exp(dtA)
    __shared__ float2 sA[NS];  // {Re(dtA), Im(dtA)/(2pi)}

    const int bid   = blockIdx.x;
    const int h     = bid >> 1;
    const int chunk = bid & 1;
    const int t     = threadIdx.x;

    // ---- Preamble: 64 threads compute the per-state discretized params ----
    if (t < NS) {
        const int m = t >> 5;   // 0..1
        const int n = t & 31;   // 0..31
        const float dt  = __expf(log_dt[h]);
        const float Are = -__expf(log_A_real[h * NST + n]);
        const float Aim = A_imag[h * NST + n];
        const float om = 1e-6f + (100.0f - 1e-6f) * (1.0f / (1.0f + __expf(-omega_logit[m])));
        const float et = 1e-6f + (10.0f  - 1e-6f) * (1.0f / (1.0f + __expf(-eta_logit[m])));
        const float Afr = fmaf(et, Are, -om);       // -omega + eta*Re(A)
        const float Afi = et * Aim;                 //          eta*Im(A)
        const float Cfr = et * C_real[(h * NST + n) * 2 + 0];
        const float Cfi = et * C_real[(h * NST + n) * 2 + 1];
        const float ar = dt * Afr, ai = dt * Afi;   // dtA
        const float e  = __expf(ar);
        float sn, cs;
        __sincosf(ai, &sn, &cs);                    // |ai| <= ~10: small arg
        const float Er = e * cs, Ei = e * sn;       // w = exp(dtA)
        // C_disc = C_frac * (exp(dtA)-1) / (A_frac + 1e-8)
        const float dr = Afr + 1e-8f, di = Afi;
        const float inv = 1.0f / fmaf(dr, dr, di * di);
        const float numr = Er - 1.0f, numi = Ei;
        const float qr = fmaf(numr, dr,  numi * di) * inv;
        const float qi = fmaf(numi, dr, -numr * di) * inv;
        float Cdr = fmaf(Cfr, qr, -(Cfi * qi));
        float Cdi = fmaf(Cfr, qi,  (Cfi * qr));
        if (sqrtf(fmaf(Afr, Afr, Afi * Afi)) < 1e-6f) {   // |A_frac| small branch
            Cdr = Cfr * dt;
            Cdi = Cfi * dt;
        }
        sP[t] = make_float4(2.0f * Cdr, 2.0f * Cdi, Er, Ei);
        sA[t] = make_float2(ar, ai * INV_TWO_PI);
    }
    __syncthreads();

    float acc[TL];
#pragma unroll
    for (int j = 0; j < TL; ++j) acc[j] = 0.0f;

    const float l0 = (float)(chunk * CHUNK_L + t * TL);

    for (int s = 0; s < NS; s += 4) {
        float yr[4], yi[4], wr[4], wi[4];
#pragma unroll
        for (int u = 0; u < 4; ++u) {
            const float4 P = sP[s + u];
            const float2 A = sA[s + u];
            const float e = __expf(A.x * l0);      // decays; underflow -> 0, fine
            float p = A.y * l0;                    // phase in revolutions
            p = p - floorf(p);                     // [0,1): cheap exact reduction
            float sn, cs;
            __sincosf(p * TWO_PI, &sn, &cs);       // arg < 2*pi: fast path only
            const float zr = e * cs, zi = e * sn;
            yr[u] = fmaf(P.x, zr, -(P.y * zi));    // y0 = (2*C_disc) * z0
            yi[u] = fmaf(P.x, zi,  (P.y * zr));
            wr[u] = P.z; wi[u] = P.w;
        }
#pragma unroll
        for (int j = 0; j < TL; ++j) {
#pragma unroll
            for (int u = 0; u < 4; ++u) {
                acc[j] += yr[u];
                if (j + 1 < TL) {                  // last update is dead, skip
                    const float nr = fmaf(yr[u], wr[u], -(yi[u] * wi[u]));
                    const float ni = fmaf(yr[u], wi[u],  (yi[u] * wr[u]));
                    yr[u] = nr; yi[u] = ni;
                }
            }
        }
    }

    float4* o = reinterpret_cast<float4*>(
        out + (size_t)h * LL + (size_t)(chunk * CHUNK_L) + (size_t)t * TL);
    o[0] = make_float4(acc[0], acc[1], acc[2], acc[3]);
}

extern "C" void kernel_launch(void* const* d_in, const int* in_sizes, int n_in,
                              void* d_out, int out_size, void* d_ws, size_t ws_size,
                              hipStream_t stream) {
    const float* C_real      = (const float*)d_in[0];
    const float* log_dt      = (const float*)d_in[1];
    const float* log_A_real  = (const float*)d_in[2];
    const float* A_imag      = (const float*)d_in[3];
    const float* omega_logit = (const float*)d_in[4];
    const float* eta_logit   = (const float*)d_in[5];
    float* out = (float*)d_out;

    loong_kernel<<<dim3(HH * NCHUNK), dim3(256), 0, stream>>>(
        C_real, log_dt, log_A_real, A_imag, omega_logit, eta_logit, out);
}

// Round 3
// 73.982 us; speedup vs baseline: 1.0900x; 1.0669x over previous
//
#include <hip/hip_runtime.h>
#include <math.h>

// Problem constants (fixed by setup_inputs in the reference)
#define HH   512
#define NST  32
#define MM   2
#define LL   2048
#define NS   (MM * NST)   // 64 fractional states per h
#define TL   8            // l per thread; 256 threads * 8 = 2048 = L

// K[h,l] = 2*Re( sum_s C_disc[h,s] * w_s^l ),  w = exp(dtA)
//
// r_s(l) = Re(Cc_s * w_s^l) obeys the exactly-stable 2nd-order recurrence
//   r(l+1) = p*r(l) + q*r(l-1),  p = 2*Re(w), q = -|w|^2
// -> 3 VALU slots per (state,l) and ZERO transcendentals in the main loop.
// Chunk-start values come from factored LDS power tables:
//   l0 = 8*tid, tid = 16*qi + ri  =>  w^l0 = (w^128)^qi * (w^8)^ri
//   T1[s][ri] = {Re,Im(w^(8ri)), Re,Im(w^(8ri+1))}
//   T2[s][qi] = {Re,Im(Cc*(w^128)^qi), p, q}
// built once per block by repeated complex multiplication (error ~20 ulp).
__global__ __launch_bounds__(256) void loong_kernel(
    const float* __restrict__ C_real,      // [1, H, NST, 2]
    const float* __restrict__ log_dt,      // [H]
    const float* __restrict__ log_A_real,  // [H, NST]
    const float* __restrict__ A_imag,      // [H, NST]
    const float* __restrict__ omega_logit, // [M]
    const float* __restrict__ eta_logit,   // [M]
    float* __restrict__ out)               // [1, H, L]
{
    __shared__ float4 sT1[NS][16];
    __shared__ float4 sT2[NS][16];

    const int h   = blockIdx.x;
    const int tid = threadIdx.x;

    // ---- Preamble: 64 threads, one state each ----
    if (tid < NS) {
        const int m = tid >> 5;
        const int n = tid & 31;
        const float dt  = expf(log_dt[h]);
        const float Are = -expf(log_A_real[h * NST + n]);
        const float Aim = A_imag[h * NST + n];
        const float om = 1e-6f + (100.0f - 1e-6f) / (1.0f + expf(-omega_logit[m]));
        const float et = 1e-6f + (10.0f  - 1e-6f) / (1.0f + expf(-eta_logit[m]));
        const float Afr = fmaf(et, Are, -om);
        const float Afi = et * Aim;
        const float Cfr = et * C_real[(h * NST + n) * 2 + 0];
        const float Cfi = et * C_real[(h * NST + n) * 2 + 1];
        const float ar = dt * Afr, ai = dt * Afi;       // dtA
        const float e = expf(ar);
        float sn, cs;
        sincosf(ai, &sn, &cs);                          // |ai| <= ~10, accurate
        const float Er = e * cs, Ei = e * sn;           // w = exp(dtA)
        // C_disc = C_frac * (exp(dtA)-1) / (A_frac + 1e-8)
        const float dr = Afr + 1e-8f, di = Afi;
        const float inv = 1.0f / fmaf(dr, dr, di * di);
        const float numr = Er - 1.0f, numi = Ei;
        const float fr = fmaf(numr, dr,  numi * di) * inv;
        const float fi = fmaf(numi, dr, -numr * di) * inv;
        float Cdr = fmaf(Cfr, fr, -(Cfi * fi));
        float Cdi = fmaf(Cfr, fi,  (Cfi * fr));
        if (sqrtf(fmaf(Afr, Afr, Afi * Afi)) < 1e-6f) { // small-|A| branch
            Cdr = Cfr * dt;
            Cdi = Cfi * dt;
        }
        const float Ccr = 2.0f * Cdr, Cci = 2.0f * Cdi; // fold the 2*Re factor
        const float p  = 2.0f * Er;
        const float qc = -fmaf(Er, Er, Ei * Ei);

        // w^8 via three complex squarings
        float w2r = fmaf(Er, Er, -(Ei * Ei)),  w2i = 2.0f * Er * Ei;
        float w4r = fmaf(w2r, w2r, -(w2i * w2i)), w4i = 2.0f * w2r * w2i;
        float w8r = fmaf(w4r, w4r, -(w4i * w4i)), w8i = 2.0f * w4r * w4i;

        // T1 chain: u = (w^8)^r ; also store u*w = w^(8r+1)
        float ur = 1.0f, ui = 0.0f;
#pragma unroll
        for (int r = 0; r < 16; ++r) {
            sT1[tid][r] = make_float4(ur, ui,
                                      fmaf(ur, Er, -(ui * Ei)),
                                      fmaf(ur, Ei,  (ui * Er)));
            const float nr = fmaf(ur, w8r, -(ui * w8i));
            const float ni = fmaf(ur, w8i,  (ui * w8r));
            ur = nr; ui = ni;
        }
        // w^128 via four more squarings
        float wr_ = w8r, wi_ = w8i;
#pragma unroll
        for (int k = 0; k < 4; ++k) {
            const float nr = fmaf(wr_, wr_, -(wi_ * wi_));
            const float ni = 2.0f * wr_ * wi_;
            wr_ = nr; wi_ = ni;
        }
        // T2 chain: v = Cc * (w^128)^q ; pack {p, qc} alongside
        float vr = Ccr, vi = Cci;
#pragma unroll
        for (int q = 0; q < 16; ++q) {
            sT2[tid][q] = make_float4(vr, vi, p, qc);
            const float nr = fmaf(vr, wr_, -(vi * wi_));
            const float ni = fmaf(vr, wi_,  (vi * wr_));
            vr = nr; vi = ni;
        }
    }
    __syncthreads();

    const int ri = tid & 15;
    const int qi = tid >> 4;

    float acc[TL];
#pragma unroll
    for (int j = 0; j < TL; ++j) acc[j] = 0.0f;

    for (int s = 0; s < NS; s += 4) {
        float4 t1[4], t2[4];
#pragma unroll
        for (int u = 0; u < 4; ++u) {
            t1[u] = sT1[s + u][ri];
            t2[u] = sT2[s + u][qi];
        }
#pragma unroll
        for (int u = 0; u < 4; ++u) {
            const float p = t2[u].z, qq = t2[u].w;
            float r0 = fmaf(t1[u].x, t2[u].x, -(t1[u].y * t2[u].y)); // Re(t*b)
            float r1 = fmaf(t1[u].z, t2[u].x, -(t1[u].w * t2[u].y)); // Re(t'*b)
            acc[0] += r0;
            acc[1] += r1;
#pragma unroll
            for (int j = 2; j < TL; ++j) {
                const float rn = fmaf(p, r1, qq * r0);
                acc[j] += rn;
                r0 = r1; r1 = rn;
            }
        }
    }

    float4* o = reinterpret_cast<float4*>(out + (size_t)h * LL + (size_t)tid * TL);
    o[0] = make_float4(acc[0], acc[1], acc[2], acc[3]);
    o[1] = make_float4(acc[4], acc[5], acc[6], acc[7]);
}

extern "C" void kernel_launch(void* const* d_in, const int* in_sizes, int n_in,
                              void* d_out, int out_size, void* d_ws, size_t ws_size,
                              hipStream_t stream) {
    const float* C_real      = (const float*)d_in[0];
    const float* log_dt      = (const float*)d_in[1];
    const float* log_A_real  = (const float*)d_in[2];
    const float* A_imag      = (const float*)d_in[3];
    const float* omega_logit = (const float*)d_in[4];
    const float* eta_logit   = (const float*)d_in[5];
    float* out = (float*)d_out;

    loong_kernel<<<dim3(HH), dim3(256), 0, stream>>>(
        C_real, log_dt, log_A_real, A_imag, omega_logit, eta_logit, out);
}